// Round 11
// baseline (443.948 us; speedup 1.0000x reference)
//
#include <hip/hip_runtime.h>

// ---------------------------------------------------------------------------
// MHA forward. B=2 L=2048 D=1024 H=16 dk=dv=64.
// d_out = [out: 4194304 f32][attn: 134217728 f32]
// ws (40MB): wq|wk|wv|wo bf16 @0,2,4,6MB; q_b@8; k_b@16; vT@24; ctx@32
// Order: cvt_w -> fused QKV (Q prescaled by 0.125/ln2) -> attn (exp2) -> out
// attn: BARRIER-FREE. K/V^T read directly global->reg as MFMA fragments
// (L1 serves intra-block reuse); only per-wave p_lds transpose in LDS.
// Attn stores NONTEMPORAL (537MB stream must not evict K/V from L2).
// ---------------------------------------------------------------------------

typedef unsigned short u16;
typedef unsigned int   u32;
typedef __attribute__((ext_vector_type(4))) float f32x4;
typedef __attribute__((ext_vector_type(8))) u16   u16x8;
typedef __attribute__((ext_vector_type(4))) u16   u16x4;
typedef __attribute__((ext_vector_type(8))) __bf16 bf16x8;

#define MFMA16(a, b, c) __builtin_amdgcn_mfma_f32_16x16x32_bf16((a), (b), (c), 0, 0, 0)
#define VMCNT0 asm volatile("s_waitcnt vmcnt(0)" ::: "memory")

#if defined(__has_builtin)
#if __has_builtin(__builtin_amdgcn_global_load_lds)
#define HAS_GLL 1
#endif
#if __has_builtin(__builtin_amdgcn_exp2f)
#define EXP2(x) __builtin_amdgcn_exp2f(x)
#endif
#endif
#ifndef HAS_GLL
#define HAS_GLL 0
#endif
#ifndef EXP2
#define EXP2(x) __expf((x) * 0.69314718056f)
#endif

#define QSCALE 0.18033688011116f   // 0.125 / ln(2)

__device__ __forceinline__ u16 f2bf(float x) {
    u32 u = __builtin_bit_cast(u32, x);
    u += 0x7fffu + ((u >> 16) & 1u);   // RNE
    return (u16)(u >> 16);
}
__device__ __forceinline__ float bf2f(u16 x) {
    u32 u = ((u32)x) << 16;
    return __builtin_bit_cast(float, u);
}
__device__ __forceinline__ bf16x8 ld8(const u16* p) {
    return __builtin_bit_cast(bf16x8, *(const u16x8*)p);
}

// async global->LDS, 16B per lane; lds_base wave-uniform, HW adds lane*16.
__device__ __forceinline__ void stage16(const u16* g, u16* lds_base, int lane) {
#if HAS_GLL
    (void)lane;
    __builtin_amdgcn_global_load_lds(
        (const __attribute__((address_space(1))) u32*)g,
        (__attribute__((address_space(3))) u32*)lds_base, 16, 0, 0);
#else
    *(u16x8*)((char*)lds_base + lane * 16) = *(const u16x8*)g;
#endif
}

// ---------------- fp32 -> bf16 conversion (weights only) -------------------
__global__ __launch_bounds__(256) void cvt_w(
    const float* __restrict__ wq, const float* __restrict__ wk,
    const float* __restrict__ wv, const float* __restrict__ wo,
    u16* __restrict__ wqb, u16* __restrict__ wkb,
    u16* __restrict__ wvb, u16* __restrict__ wob) {
    int bid = blockIdx.x;
    const float* src; u16* dst; int base;
    if      (bid < 1024) { src = wq; dst = wqb; base = bid; }
    else if (bid < 2048) { src = wk; dst = wkb; base = bid - 1024; }
    else if (bid < 3072) { src = wv; dst = wvb; base = bid - 2048; }
    else                 { src = wo; dst = wob; base = bid - 3072; }
    int i = (base * 256 + threadIdx.x) * 4;
    float4 v = *(const float4*)(src + i);
    u16x4 h = { f2bf(v.x), f2bf(v.y), f2bf(v.z), f2bf(v.w) };
    *(u16x4*)(dst + i) = h;
}

// ---------------- fused QKV projection (round-8 proven) --------------------
__global__ __launch_bounds__(256)
void k_qkv(const float* __restrict__ qa, const float* __restrict__ ka,
           const float* __restrict__ va,
           const u16* __restrict__ wqp, const u16* __restrict__ wkp,
           const u16* __restrict__ wvp,
           u16* __restrict__ qo, u16* __restrict__ ko, u16* __restrict__ vTo) {
    constexpr int K = 1024;
    __shared__ u16 act_lds[2][128][32];
    __shared__ u16 w_lds[2][128][32];

    const int tid = threadIdx.x, lane = tid & 63, w = tid >> 6;
    const int wr = w >> 1, wc = w & 1, lr = lane & 15, g0 = lane >> 4;
    const int bid = blockIdx.x, region = bid >> 8, r = bid & 255;
    const int act_r0 = (r >> 3) * 128, w_r0 = (r & 7) * 128;

    const float* actp = region == 0 ? qa : region == 1 ? ka : va;
    const u16*   wp   = region == 0 ? wqp : region == 1 ? wkp : wvp;

    const int srow = lane >> 2;
    const int scol = ((lane & 3) ^ ((lane >> 3) & 3)) * 8;
    const int arow = tid >> 1, ac0 = (tid & 1) * 16, lg0 = (tid & 1) * 2;
    const int apg0 = ((lg0)     ^ ((arow >> 1) & 3)) * 8;
    const int apg1 = ((lg0 + 1) ^ ((arow >> 1) & 3)) * 8;
    const int aph = (g0 ^ ((lr >> 1) & 3)) * 8;

    auto stage = [&](int kt, int buf) {
        #pragma unroll
        for (int c = 0; c < 2; ++c) {
            int rb = w * 16 + c * 64;
            stage16(wp + (size_t)(w_r0 + rb + srow) * K + kt * 32 + scol,
                    &w_lds[buf][rb][0], lane);
        }
        const float* as = actp + (size_t)(act_r0 + arow) * K + kt * 32 + ac0;
        f32x4 v0 = *(const f32x4*)as;
        f32x4 v1 = *(const f32x4*)(as + 4);
        f32x4 v2 = *(const f32x4*)(as + 8);
        f32x4 v3 = *(const f32x4*)(as + 12);
        u16x8 h0 = { f2bf(v0[0]), f2bf(v0[1]), f2bf(v0[2]), f2bf(v0[3]),
                     f2bf(v1[0]), f2bf(v1[1]), f2bf(v1[2]), f2bf(v1[3]) };
        u16x8 h1 = { f2bf(v2[0]), f2bf(v2[1]), f2bf(v2[2]), f2bf(v2[3]),
                     f2bf(v3[0]), f2bf(v3[1]), f2bf(v3[2]), f2bf(v3[3]) };
        *(u16x8*)&act_lds[buf][arow][apg0] = h0;
        *(u16x8*)&act_lds[buf][arow][apg1] = h1;
    };

    f32x4 acc[4][4] = {};
    stage(0, 0);
    VMCNT0;
    __syncthreads();

    for (int kt = 0; kt < 32; ++kt) {
        if (kt + 1 < 32) stage(kt + 1, (kt + 1) & 1);
        const int buf = kt & 1;
        const u16 (*ml)[32] = (region < 2) ? act_lds[buf] : w_lds[buf];
        const u16 (*nl)[32] = (region < 2) ? w_lds[buf]   : act_lds[buf];
        bf16x8 mf[4], nf[4];
        #pragma unroll
        for (int m = 0; m < 4; ++m) mf[m] = ld8(&ml[wr * 64 + m * 16 + lr][aph]);
        #pragma unroll
        for (int n = 0; n < 4; ++n) nf[n] = ld8(&nl[wc * 64 + n * 16 + lr][aph]);
        #pragma unroll
        for (int m = 0; m < 4; ++m)
            #pragma unroll
            for (int n = 0; n < 4; ++n)
                acc[m][n] = MFMA16(mf[m], nf[n], acc[m][n]);
        VMCNT0;
        __syncthreads();
    }

    const float sc = (region == 0) ? QSCALE : 1.0f;   // fold softmax scale into Q
    if (region < 2) {
        u16* dst = region == 0 ? qo : ko;
        #pragma unroll
        for (int m = 0; m < 4; ++m)
            #pragma unroll
            for (int n = 0; n < 4; ++n)
                #pragma unroll
                for (int rr = 0; rr < 4; ++rr) {
                    int grow = act_r0 + wr * 64 + m * 16 + g0 * 4 + rr;
                    int gcol = w_r0 + wc * 64 + n * 16 + lr;
                    size_t di = (size_t)((grow >> 11) * 16 + (gcol >> 6)) * 131072
                              + (size_t)(grow & 2047) * 64 + (gcol & 63);
                    dst[di] = f2bf(acc[m][n][rr] * sc);
                }
    } else {
        #pragma unroll
        for (int m = 0; m < 4; ++m)
            #pragma unroll
            for (int n = 0; n < 4; ++n)
                #pragma unroll
                for (int rr = 0; rr < 4; ++rr) {
                    int dvi = w_r0 + wr * 64 + m * 16 + g0 * 4 + rr;
                    int li  = act_r0 + wc * 64 + n * 16 + lr;
                    vTo[(size_t)dvi * 4096 + li] = f2bf(acc[m][n][rr]);
                }
    }
}

// ---------------- out projection (round-7 proven, unchanged) ---------------
__global__ __launch_bounds__(256)
void k_out(const u16* __restrict__ A, const u16* __restrict__ Bw,
           float* __restrict__ C) {
    constexpr int K = 1024;
    __shared__ u16 a_lds[2][128][32];
    __shared__ u16 b_lds[2][64][32];

    const int tid = threadIdx.x, lane = tid & 63, w = tid >> 6;
    const int wr = w >> 1, wc = w & 1, lr = lane & 15, g0 = lane >> 4;
    const int m0 = blockIdx.y * 128, n0 = blockIdx.x * 64;

    const int srow = lane >> 2;
    const int scol = ((lane & 3) ^ ((lane >> 3) & 3)) * 8;
    const int aph = (g0 ^ ((lr >> 1) & 3)) * 8;

    auto stage = [&](int kt, int buf) {
        #pragma unroll
        for (int c = 0; c < 2; ++c) {
            int rb = w * 16 + c * 64;
            stage16(A + (size_t)(m0 + rb + srow) * K + kt * 32 + scol,
                    &a_lds[buf][rb][0], lane);
        }
        int rb2 = w * 16;
        stage16(Bw + (size_t)(n0 + rb2 + srow) * K + kt * 32 + scol,
                &b_lds[buf][rb2][0], lane);
    };

    f32x4 acc[4][2] = {};
    stage(0, 0);
    VMCNT0;
    __syncthreads();

    for (int kt = 0; kt < 32; ++kt) {
        if (kt + 1 < 32) stage(kt + 1, (kt + 1) & 1);
        const int buf = kt & 1;
        bf16x8 mf[4], nf[2];
        #pragma unroll
        for (int m = 0; m < 4; ++m) mf[m] = ld8(&a_lds[buf][wr * 64 + m * 16 + lr][aph]);
        #pragma unroll
        for (int n = 0; n < 2; ++n) nf[n] = ld8(&b_lds[buf][wc * 32 + n * 16 + lr][aph]);
        #pragma unroll
        for (int m = 0; m < 4; ++m)
            #pragma unroll
            for (int n = 0; n < 2; ++n)
                acc[m][n] = MFMA16(mf[m], nf[n], acc[m][n]);
        VMCNT0;
        __syncthreads();
    }

    #pragma unroll
    for (int m = 0; m < 4; ++m)
        #pragma unroll
        for (int n = 0; n < 2; ++n)
            #pragma unroll
            for (int rr = 0; rr < 4; ++rr) {
                int grow = m0 + wr * 64 + m * 16 + g0 * 4 + rr;
                int gcol = n0 + wc * 32 + n * 16 + lr;
                C[(size_t)grow * 1024 + gcol] = acc[m][n][rr];
            }
}

// ---------------- fused attention: barrier-free, K/V global->reg -----------
// 1024 blocks XCD-pinned, 4 independent waves x 16 q-rows. NO __syncthreads.
// K frag: lane reads K[kv+16n+lr][g0*8 (+32)] (16B). V^T frag: lane reads
// V^T[16n2+lr][kv+kk*32+g0*8]. 4 waves/block re-read same 8KB tiles -> L1 hits.
// p_lds is per-wave (same-wave ds write->read, compiler lgkmcnt only).
__global__ __launch_bounds__(256)
void attn_kernel(const u16* __restrict__ qw, const u16* __restrict__ kw,
                 const u16* __restrict__ vT, float* __restrict__ attn_o,
                 u16* __restrict__ ctx_o) {
    constexpr int L = 2048;
    __shared__ u16 p_lds[4][16][72];

    const int tid = threadIdx.x, w = tid >> 6, lane = tid & 63;
    const int bid = blockIdx.x;
    const int bh = (bid & 7) + 8 * (bid >> 8);     // XCD-pinned
    const int qb = (bid >> 3) & 31;
    const int b = bh >> 4, h = bh & 15;
    const int qr0 = qb * 64 + w * 16;
    const int lr = lane & 15, g0 = lane >> 4;

    const u16* kbh = kw + (size_t)bh * L * 64;
    const u16* vbh = vT + (size_t)(h * 64) * 4096 + b * 2048;

    size_t qbase = ((size_t)bh * L + qr0 + lr) * 64 + g0 * 8;
    bf16x8 aq0 = ld8(qw + qbase);
    bf16x8 aq1 = ld8(qw + qbase + 32);

    // per-lane fragment bases
    const u16* kfb = kbh + (size_t)lr * 64 + g0 * 8;        // + (kv+16n)*64 [+32]
    const u16* vfb = vbh + (size_t)lr * 4096 + g0 * 8;      // + n2*16*4096 + kv + kk*32

    // ---------------- phase 1: softmax denominator (m = 0) ----------------
    float ssum = 0.f;
    for (int t = 0; t < 32; ++t) {
        const int kv = t * 64;
        f32x4 sacc[4] = {};
        #pragma unroll
        for (int n = 0; n < 4; ++n) {
            const u16* kr = kfb + (size_t)(kv + n * 16) * 64;
            sacc[n] = MFMA16(ld8(kr), aq0, sacc[n]);        // swapped: S^T
            sacc[n] = MFMA16(ld8(kr + 32), aq1, sacc[n]);
        }
        #pragma unroll
        for (int n = 0; n < 4; ++n)
            #pragma unroll
            for (int rr = 0; rr < 4; ++rr)
                ssum += EXP2(sacc[n][rr]);
    }
    ssum += __shfl_xor(ssum, 16);
    ssum += __shfl_xor(ssum, 32);
    const float rinv = 1.f / ssum;     // denominator for q-row qr0+lr

    // ---------------- phase 2: attn write + PV ----------------
    f32x4 cacc[4] = {};
    float* attn_b = attn_o + (size_t)bh * L * L;

    for (int t = 0; t < 32; ++t) {
        const int kv = t * 64;
        // QK^T on current tile (K frags straight from global/L1)
        f32x4 sacc[4] = {};
        #pragma unroll
        for (int n = 0; n < 4; ++n) {
            const u16* kr = kfb + (size_t)(kv + n * 16) * 64;
            sacc[n] = MFMA16(ld8(kr), aq0, sacc[n]);
            sacc[n] = MFMA16(ld8(kr + 32), aq1, sacc[n]);
        }
        // normalized P (bf16) -> p_lds[q=lr][kv]  (per-wave array)
        #pragma unroll
        for (int n = 0; n < 4; ++n) {
            float p0 = EXP2(sacc[n][0]) * rinv;
            float p1 = EXP2(sacc[n][1]) * rinv;
            float p2 = EXP2(sacc[n][2]) * rinv;
            float p3 = EXP2(sacc[n][3]) * rinv;
            u16x4 pk = { f2bf(p0), f2bf(p1), f2bf(p2), f2bf(p3) };
            *(u16x4*)&p_lds[w][lr][n * 16 + g0 * 4] = pk;
        }
        // PV: ctx[q][dv] += P[q][kv] * V^T[dv][kv] (V frags from global/L1)
        #pragma unroll
        for (int kk = 0; kk < 2; ++kk) {
            bf16x8 ap = ld8(&p_lds[w][lr][kk * 32 + g0 * 8]);
            #pragma unroll
            for (int n2 = 0; n2 < 4; ++n2) {
                bf16x8 bv = ld8(vfb + (size_t)(n2 * 16) * 4096 + kv + kk * 32);
                cacc[n2] = MFMA16(ap, bv, cacc[n2]);
            }
        }
        // coalesced NT writeout: 4 rows x 256B per pass
        #pragma unroll
        for (int rep = 0; rep < 4; ++rep) {
            int row = rep * 4 + g0;
            u16x4 pv4 = *(const u16x4*)&p_lds[w][row][lr * 4];
            f32x4 f0 = { bf2f(pv4[0]), bf2f(pv4[1]), bf2f(pv4[2]), bf2f(pv4[3]) };
            __builtin_nontemporal_store(
                f0, (f32x4*)(attn_b + (size_t)(qr0 + row) * L + kv + lr * 4));
        }
    }

    // ctx -> ws in [b][l][h*64+dv] layout (normal stores; consumed by k_out)
    #pragma unroll
    for (int n2 = 0; n2 < 4; ++n2)
        #pragma unroll
        for (int rr = 0; rr < 4; ++rr)
            ctx_o[((size_t)b * L + qr0 + g0 * 4 + rr) * 1024 + h * 64 + n2 * 16 + lr]
                = f2bf(cacc[n2][rr]);
}

// ---------------------------------------------------------------------------
extern "C" void kernel_launch(void* const* d_in, const int* in_sizes, int n_in,
                              void* d_out, int out_size, void* d_ws, size_t ws_size,
                              hipStream_t stream) {
    const float* key   = (const float*)d_in[0];
    const float* value = (const float*)d_in[1];
    const float* query = (const float*)d_in[2];
    const float* wq    = (const float*)d_in[3];
    const float* wk    = (const float*)d_in[4];
    const float* wv    = (const float*)d_in[5];
    const float* wo    = (const float*)d_in[6];

    char* ws = (char*)d_ws;
    const size_t MB = 1024 * 1024;
    u16* wq_b = (u16*)(ws + 0 * MB);
    u16* wk_b = (u16*)(ws + 2 * MB);
    u16* wv_b = (u16*)(ws + 4 * MB);
    u16* wo_b = (u16*)(ws + 6 * MB);
    u16* q_b  = (u16*)(ws + 8 * MB);
    u16* k_b  = (u16*)(ws + 16 * MB);
    u16* vT_b = (u16*)(ws + 24 * MB);
    u16* ctx_b= (u16*)(ws + 32 * MB);

    cvt_w<<<4096, 256, 0, stream>>>(wq, wk, wv, wo, wq_b, wk_b, wv_b, wo_b);

    k_qkv<<<768, 256, 0, stream>>>(query, key, value, wq_b, wk_b, wv_b,
                                   q_b, k_b, vT_b);

    float* attn_out = (float*)d_out + 4194304;
    attn_kernel<<<dim3(1024), 256, 0, stream>>>(q_b, k_b, vT_b, attn_out, ctx_b);

    k_out<<<dim3(16, 32), 256, 0, stream>>>(ctx_b, wo_b, (float*)d_out);
}

// Round 12
// 209.851 us; speedup vs baseline: 2.1155x; 2.1155x over previous
//
#include <hip/hip_runtime.h>

// ---------------------------------------------------------------------------
// MHA forward. B=2 L=2048 D=1024 H=16 dk=dv=64.
// d_out = [out: 4194304 f32][attn: 134217728 f32]
// ws (40MB): wq|wk|wv|wo bf16 @0,2,4,6MB; q_b@8; k_b@16; vT@24; ctx@32
// Order: cvt_w -> fused QKV (Q prescaled by 0.125/ln2) -> attn (exp2) -> out
// attn = R10 structure (LDS-staged, counted-vmcnt store pipeline, NT stores).
// k_qkv / k_out: XCD-pinned block remaps (panel-sharing blocks -> same L2).
// ---------------------------------------------------------------------------

typedef unsigned short u16;
typedef unsigned int   u32;
typedef __attribute__((ext_vector_type(4))) float f32x4;
typedef __attribute__((ext_vector_type(8))) u16   u16x8;
typedef __attribute__((ext_vector_type(4))) u16   u16x4;
typedef __attribute__((ext_vector_type(8))) __bf16 bf16x8;

#define MFMA16(a, b, c) __builtin_amdgcn_mfma_f32_16x16x32_bf16((a), (b), (c), 0, 0, 0)
#define VMCNT0 asm volatile("s_waitcnt vmcnt(0)" ::: "memory")
#define VMCNT4 asm volatile("s_waitcnt vmcnt(4)" ::: "memory")
#define LGKM0  asm volatile("s_waitcnt lgkmcnt(0)" ::: "memory")
#define SCHED0 __builtin_amdgcn_sched_barrier(0)
#define RAWBAR __builtin_amdgcn_s_barrier()

#if defined(__has_builtin)
#if __has_builtin(__builtin_amdgcn_global_load_lds)
#define HAS_GLL 1
#endif
#if __has_builtin(__builtin_amdgcn_exp2f)
#define EXP2(x) __builtin_amdgcn_exp2f(x)
#endif
#endif
#ifndef HAS_GLL
#define HAS_GLL 0
#endif
#ifndef EXP2
#define EXP2(x) __expf((x) * 0.69314718056f)
#endif

#define QSCALE 0.18033688011116f   // 0.125 / ln(2)

__device__ __forceinline__ u16 f2bf(float x) {
    u32 u = __builtin_bit_cast(u32, x);
    u += 0x7fffu + ((u >> 16) & 1u);   // RNE
    return (u16)(u >> 16);
}
__device__ __forceinline__ float bf2f(u16 x) {
    u32 u = ((u32)x) << 16;
    return __builtin_bit_cast(float, u);
}
__device__ __forceinline__ bf16x8 ld8(const u16* p) {
    return __builtin_bit_cast(bf16x8, *(const u16x8*)p);
}

// async global->LDS, 16B per lane; lds_base wave-uniform, HW adds lane*16.
__device__ __forceinline__ void stage16(const u16* g, u16* lds_base, int lane) {
#if HAS_GLL
    (void)lane;
    __builtin_amdgcn_global_load_lds(
        (const __attribute__((address_space(1))) u32*)g,
        (__attribute__((address_space(3))) u32*)lds_base, 16, 0, 0);
#else
    *(u16x8*)((char*)lds_base + lane * 16) = *(const u16x8*)g;
#endif
}

// ---------------- fp32 -> bf16 conversion (weights only) -------------------
__global__ __launch_bounds__(256) void cvt_w(
    const float* __restrict__ wq, const float* __restrict__ wk,
    const float* __restrict__ wv, const float* __restrict__ wo,
    u16* __restrict__ wqb, u16* __restrict__ wkb,
    u16* __restrict__ wvb, u16* __restrict__ wob) {
    int bid = blockIdx.x;
    const float* src; u16* dst; int base;
    if      (bid < 1024) { src = wq; dst = wqb; base = bid; }
    else if (bid < 2048) { src = wk; dst = wkb; base = bid - 1024; }
    else if (bid < 3072) { src = wv; dst = wvb; base = bid - 2048; }
    else                 { src = wo; dst = wob; base = bid - 3072; }
    int i = (base * 256 + threadIdx.x) * 4;
    float4 v = *(const float4*)(src + i);
    u16x4 h = { f2bf(v.x), f2bf(v.y), f2bf(v.z), f2bf(v.w) };
    *(u16x4*)(dst + i) = h;
}

// ---------------- fused QKV projection (round-8 proven, XCD-pinned) --------
// bid = k*96 + g (bijective): g = act-group (region*32 + act_idx), k = w-tile.
// All 8 w-tiles of an act panel share bid%8 -> same XCD L2 serves the panel.
__global__ __launch_bounds__(256)
void k_qkv(const float* __restrict__ qa, const float* __restrict__ ka,
           const float* __restrict__ va,
           const u16* __restrict__ wqp, const u16* __restrict__ wkp,
           const u16* __restrict__ wvp,
           u16* __restrict__ qo, u16* __restrict__ ko, u16* __restrict__ vTo) {
    constexpr int K = 1024;
    __shared__ u16 act_lds[2][128][32];
    __shared__ u16 w_lds[2][128][32];

    const int tid = threadIdx.x, lane = tid & 63, w = tid >> 6;
    const int wr = w >> 1, wc = w & 1, lr = lane & 15, g0 = lane >> 4;
    const int bid0 = blockIdx.x;
    const int kk = bid0 / 96, gg = bid0 % 96;      // XCD-pinned remap
    const int wgid = gg * 8 + kk;
    const int region = wgid >> 8, r = wgid & 255;
    const int act_r0 = (r >> 3) * 128, w_r0 = (r & 7) * 128;

    const float* actp = region == 0 ? qa : region == 1 ? ka : va;
    const u16*   wp   = region == 0 ? wqp : region == 1 ? wkp : wvp;

    const int srow = lane >> 2;
    const int scol = ((lane & 3) ^ ((lane >> 3) & 3)) * 8;
    const int arow = tid >> 1, ac0 = (tid & 1) * 16, lg0 = (tid & 1) * 2;
    const int apg0 = ((lg0)     ^ ((arow >> 1) & 3)) * 8;
    const int apg1 = ((lg0 + 1) ^ ((arow >> 1) & 3)) * 8;
    const int aph = (g0 ^ ((lr >> 1) & 3)) * 8;

    auto stage = [&](int kt, int buf) {
        #pragma unroll
        for (int c = 0; c < 2; ++c) {
            int rb = w * 16 + c * 64;
            stage16(wp + (size_t)(w_r0 + rb + srow) * K + kt * 32 + scol,
                    &w_lds[buf][rb][0], lane);
        }
        const float* as = actp + (size_t)(act_r0 + arow) * K + kt * 32 + ac0;
        f32x4 v0 = *(const f32x4*)as;
        f32x4 v1 = *(const f32x4*)(as + 4);
        f32x4 v2 = *(const f32x4*)(as + 8);
        f32x4 v3 = *(const f32x4*)(as + 12);
        u16x8 h0 = { f2bf(v0[0]), f2bf(v0[1]), f2bf(v0[2]), f2bf(v0[3]),
                     f2bf(v1[0]), f2bf(v1[1]), f2bf(v1[2]), f2bf(v1[3]) };
        u16x8 h1 = { f2bf(v2[0]), f2bf(v2[1]), f2bf(v2[2]), f2bf(v2[3]),
                     f2bf(v3[0]), f2bf(v3[1]), f2bf(v3[2]), f2bf(v3[3]) };
        *(u16x8*)&act_lds[buf][arow][apg0] = h0;
        *(u16x8*)&act_lds[buf][arow][apg1] = h1;
    };

    f32x4 acc[4][4] = {};
    stage(0, 0);
    VMCNT0;
    __syncthreads();

    for (int kt = 0; kt < 32; ++kt) {
        if (kt + 1 < 32) stage(kt + 1, (kt + 1) & 1);
        const int buf = kt & 1;
        const u16 (*ml)[32] = (region < 2) ? act_lds[buf] : w_lds[buf];
        const u16 (*nl)[32] = (region < 2) ? w_lds[buf]   : act_lds[buf];
        bf16x8 mf[4], nf[4];
        #pragma unroll
        for (int m = 0; m < 4; ++m) mf[m] = ld8(&ml[wr * 64 + m * 16 + lr][aph]);
        #pragma unroll
        for (int n = 0; n < 4; ++n) nf[n] = ld8(&nl[wc * 64 + n * 16 + lr][aph]);
        #pragma unroll
        for (int m = 0; m < 4; ++m)
            #pragma unroll
            for (int n = 0; n < 4; ++n)
                acc[m][n] = MFMA16(mf[m], nf[n], acc[m][n]);
        VMCNT0;
        __syncthreads();
    }

    const float sc = (region == 0) ? QSCALE : 1.0f;   // fold softmax scale into Q
    if (region < 2) {
        u16* dst = region == 0 ? qo : ko;
        #pragma unroll
        for (int m = 0; m < 4; ++m)
            #pragma unroll
            for (int n = 0; n < 4; ++n)
                #pragma unroll
                for (int rr = 0; rr < 4; ++rr) {
                    int grow = act_r0 + wr * 64 + m * 16 + g0 * 4 + rr;
                    int gcol = w_r0 + wc * 64 + n * 16 + lr;
                    size_t di = (size_t)((grow >> 11) * 16 + (gcol >> 6)) * 131072
                              + (size_t)(grow & 2047) * 64 + (gcol & 63);
                    dst[di] = f2bf(acc[m][n][rr] * sc);
                }
    } else {
        #pragma unroll
        for (int m = 0; m < 4; ++m)
            #pragma unroll
            for (int n = 0; n < 4; ++n)
                #pragma unroll
                for (int rr = 0; rr < 4; ++rr) {
                    int dvi = w_r0 + wr * 64 + m * 16 + g0 * 4 + rr;
                    int li  = act_r0 + wc * 64 + n * 16 + lr;
                    vTo[(size_t)dvi * 4096 + li] = f2bf(acc[m][n][rr]);
                }
    }
}

// ---------------- out projection (round-7 proven, XCD-pinned 1D grid) ------
// bid = n_idx*32 + m_g: the 16 n-blocks of one ctx panel share bid%8 -> one XCD.
__global__ __launch_bounds__(256)
void k_out(const u16* __restrict__ A, const u16* __restrict__ Bw,
           float* __restrict__ C) {
    constexpr int K = 1024;
    __shared__ u16 a_lds[2][128][32];
    __shared__ u16 b_lds[2][64][32];

    const int tid = threadIdx.x, lane = tid & 63, w = tid >> 6;
    const int wr = w >> 1, wc = w & 1, lr = lane & 15, g0 = lane >> 4;
    const int bid = blockIdx.x;
    const int m0 = (bid & 31) * 128, n0 = (bid >> 5) * 64;

    const int srow = lane >> 2;
    const int scol = ((lane & 3) ^ ((lane >> 3) & 3)) * 8;
    const int aph = (g0 ^ ((lr >> 1) & 3)) * 8;

    auto stage = [&](int kt, int buf) {
        #pragma unroll
        for (int c = 0; c < 2; ++c) {
            int rb = w * 16 + c * 64;
            stage16(A + (size_t)(m0 + rb + srow) * K + kt * 32 + scol,
                    &a_lds[buf][rb][0], lane);
        }
        int rb2 = w * 16;
        stage16(Bw + (size_t)(n0 + rb2 + srow) * K + kt * 32 + scol,
                &b_lds[buf][rb2][0], lane);
    };

    f32x4 acc[4][2] = {};
    stage(0, 0);
    VMCNT0;
    __syncthreads();

    for (int kt = 0; kt < 32; ++kt) {
        if (kt + 1 < 32) stage(kt + 1, (kt + 1) & 1);
        const int buf = kt & 1;
        bf16x8 mf[4], nf[2];
        #pragma unroll
        for (int m = 0; m < 4; ++m) mf[m] = ld8(&a_lds[buf][wr * 64 + m * 16 + lr][aph]);
        #pragma unroll
        for (int n = 0; n < 2; ++n) nf[n] = ld8(&b_lds[buf][wc * 32 + n * 16 + lr][aph]);
        #pragma unroll
        for (int m = 0; m < 4; ++m)
            #pragma unroll
            for (int n = 0; n < 2; ++n)
                acc[m][n] = MFMA16(mf[m], nf[n], acc[m][n]);
        VMCNT0;
        __syncthreads();
    }

    #pragma unroll
    for (int m = 0; m < 4; ++m)
        #pragma unroll
        for (int n = 0; n < 2; ++n)
            #pragma unroll
            for (int rr = 0; rr < 4; ++rr) {
                int grow = m0 + wr * 64 + m * 16 + g0 * 4 + rr;
                int gcol = n0 + wc * 32 + n * 16 + lr;
                C[(size_t)grow * 1024 + gcol] = acc[m][n][rr];
            }
}

// ---------------- fused attention: R10 verbatim ----------------------------
// 1024 blocks XCD-pinned, 4 waves x 16 q-rows, 4 blocks/CU (33.2 KB LDS).
// Phase 2: loads (V(t),K(t+1)) first, then NT stores(t-1); after QK wait
// vmcnt(4) = drain loads, stores stay in flight; raw s_barrier (no full drain).
__global__ __launch_bounds__(256, 4)
void attn_kernel(const u16* __restrict__ qw, const u16* __restrict__ kw,
                 const u16* __restrict__ vT, float* __restrict__ attn_o,
                 u16* __restrict__ ctx_o) {
    constexpr int L = 2048;
    __shared__ u16 k_lds[2][64][64];
    __shared__ u16 vt_lds[64][64];
    __shared__ u16 p_lds[4][16][72];

    const int tid = threadIdx.x, w = tid >> 6, lane = tid & 63;
    const int bid = blockIdx.x;
    const int bh = (bid & 7) + 8 * (bid >> 8);     // XCD-pinned
    const int qb = (bid >> 3) & 31;
    const int b = bh >> 4, h = bh & 15;
    const int qr0 = qb * 64 + w * 16;
    const int lr = lane & 15, g0 = lane >> 4;

    const u16* kbh = kw + (size_t)bh * L * 64;
    const u16* vbh = vT + (size_t)(h * 64) * 4096 + b * 2048;

    const int srow8 = lane >> 3;                   // 0..7
    const int scol8 = ((lane & 7) ^ srow8) * 8;    // pre-swizzled src granule
    const int kph0 = (g0 ^ (lr & 7)) * 8;
    const int kph1 = ((g0 + 4) ^ (lr & 7)) * 8;

    size_t qbase = ((size_t)bh * L + qr0 + lr) * 64 + g0 * 8;
    bf16x8 aq0 = ld8(qw + qbase);
    bf16x8 aq1 = ld8(qw + qbase + 32);

    auto stageK = [&](int kv, int buf) {
        #pragma unroll
        for (int c = 0; c < 2; ++c) {
            int rb = c * 32 + w * 8;
            stage16(kbh + (size_t)(kv + rb + srow8) * 64 + scol8,
                    &k_lds[buf][rb][0], lane);
        }
    };
    auto stageV = [&](int kv) {
        #pragma unroll
        for (int c = 0; c < 2; ++c) {
            int rb = w * 16 + c * 8;
            stage16(vbh + (size_t)(rb + srow8) * 4096 + kv + scol8,
                    &vt_lds[rb][0], lane);
        }
    };

    // ---------------- phase 1: softmax denominator ----------------
    float ssum = 0.f;
    stageK(0, 0);
    VMCNT0;
    __syncthreads();
    for (int t = 0; t < 32; ++t) {
        if (t + 1 < 32) stageK((t + 1) * 64, (t + 1) & 1);
        const int buf = t & 1;
        f32x4 sacc[4] = {};
        #pragma unroll
        for (int n = 0; n < 4; ++n) {
            const u16* krow = &k_lds[buf][n * 16 + lr][0];
            sacc[n] = MFMA16(ld8(krow + kph0), aq0, sacc[n]);   // swapped: S^T
            sacc[n] = MFMA16(ld8(krow + kph1), aq1, sacc[n]);
        }
        #pragma unroll
        for (int n = 0; n < 4; ++n)
            #pragma unroll
            for (int rr = 0; rr < 4; ++rr)
                ssum += EXP2(sacc[n][rr]);
        VMCNT0;            // drain t+1 prefetch
        __syncthreads();
    }
    ssum += __shfl_xor(ssum, 16);
    ssum += __shfl_xor(ssum, 32);
    const float rinv = 1.f / ssum;

    // ---------------- phase 2: attn write + PV ----------------
    f32x4 cacc[4] = {};
    float* attn_b = attn_o + (size_t)bh * L * L;
    stageK(0, 0);
    VMCNT0;
    __syncthreads();

    for (int t = 0; t < 32; ++t) {
        const int kv = t * 64, buf = t & 1;
        // loads FIRST (oldest in vm queue -> drained by vmcnt(4))
        stageV(kv);
        if (t + 1 < 32) stageK(kv + 64, buf ^ 1);
        SCHED0;                        // keep stores below the gll issues
        // deferred NT writeout of tile t-1 (stores stay in flight past barrier)
        if (t > 0) {
            const int kvp = kv - 64;
            #pragma unroll
            for (int rep = 0; rep < 4; ++rep) {
                int row = rep * 4 + g0;
                u16x4 pv4 = *(const u16x4*)&p_lds[w][row][lr * 4];
                f32x4 f0 = { bf2f(pv4[0]), bf2f(pv4[1]), bf2f(pv4[2]), bf2f(pv4[3]) };
                __builtin_nontemporal_store(
                    f0, (f32x4*)(attn_b + (size_t)(qr0 + row) * L + kvp + lr * 4));
            }
        }
        // QK^T on current tile
        f32x4 sacc[4] = {};
        #pragma unroll
        for (int n = 0; n < 4; ++n) {
            const u16* krow = &k_lds[buf][n * 16 + lr][0];
            sacc[n] = MFMA16(ld8(krow + kph0), aq0, sacc[n]);
            sacc[n] = MFMA16(ld8(krow + kph1), aq1, sacc[n]);
        }
        // drain the 4 gll loads; allow the 4 stores to stay in flight
        if (t == 0) { VMCNT0; } else { VMCNT4; }
        SCHED0; RAWBAR; SCHED0;        // mid barrier (no full vm drain)

        // normalized P (bf16) -> p_lds[q=lr][kv]
        #pragma unroll
        for (int n = 0; n < 4; ++n) {
            float p0 = EXP2(sacc[n][0]) * rinv;
            float p1 = EXP2(sacc[n][1]) * rinv;
            float p2 = EXP2(sacc[n][2]) * rinv;
            float p3 = EXP2(sacc[n][3]) * rinv;
            u16x4 pk = { f2bf(p0), f2bf(p1), f2bf(p2), f2bf(p3) };
            *(u16x4*)&p_lds[w][lr][n * 16 + g0 * 4] = pk;
        }
        // PV: ctx[q][dv] += P[q][kv] * V^T[dv][kv]
        #pragma unroll
        for (int kk = 0; kk < 2; ++kk) {
            bf16x8 ap = ld8(&p_lds[w][lr][kk * 32 + g0 * 8]);
            const int vph = ((kk * 4 + g0) ^ (lr & 7)) * 8;
            #pragma unroll
            for (int n2 = 0; n2 < 4; ++n2) {
                bf16x8 bv = ld8(&vt_lds[n2 * 16 + lr][vph]);
                cacc[n2] = MFMA16(ap, bv, cacc[n2]);
            }
        }
        LGKM0;                          // DS retired -> vt_lds/k_lds safe to restage
        SCHED0; RAWBAR; SCHED0;         // end barrier (stores still in flight)
    }
    // final NT writeout (tile 31)
    #pragma unroll
    for (int rep = 0; rep < 4; ++rep) {
        int row = rep * 4 + g0;
        u16x4 pv4 = *(const u16x4*)&p_lds[w][row][lr * 4];
        f32x4 f0 = { bf2f(pv4[0]), bf2f(pv4[1]), bf2f(pv4[2]), bf2f(pv4[3]) };
        __builtin_nontemporal_store(
            f0, (f32x4*)(attn_b + (size_t)(qr0 + row) * L + (L - 64) + lr * 4));
    }

    // ctx -> ws in [b][l][h*64+dv] layout (normal stores; consumed by k_out)
    #pragma unroll
    for (int n2 = 0; n2 < 4; ++n2)
        #pragma unroll
        for (int rr = 0; rr < 4; ++rr)
            ctx_o[((size_t)b * L + qr0 + g0 * 4 + rr) * 1024 + h * 64 + n2 * 16 + lr]
                = f2bf(cacc[n2][rr]);
}

// ---------------------------------------------------------------------------
extern "C" void kernel_launch(void* const* d_in, const int* in_sizes, int n_in,
                              void* d_out, int out_size, void* d_ws, size_t ws_size,
                              hipStream_t stream) {
    const float* key   = (const float*)d_in[0];
    const float* value = (const float*)d_in[1];
    const float* query = (const float*)d_in[2];
    const float* wq    = (const float*)d_in[3];
    const float* wk    = (const float*)d_in[4];
    const float* wv    = (const float*)d_in[5];
    const float* wo    = (const float*)d_in[6];

    char* ws = (char*)d_ws;
    const size_t MB = 1024 * 1024;
    u16* wq_b = (u16*)(ws + 0 * MB);
    u16* wk_b = (u16*)(ws + 2 * MB);
    u16* wv_b = (u16*)(ws + 4 * MB);
    u16* wo_b = (u16*)(ws + 6 * MB);
    u16* q_b  = (u16*)(ws + 8 * MB);
    u16* k_b  = (u16*)(ws + 16 * MB);
    u16* vT_b = (u16*)(ws + 24 * MB);
    u16* ctx_b= (u16*)(ws + 32 * MB);

    cvt_w<<<4096, 256, 0, stream>>>(wq, wk, wv, wo, wq_b, wk_b, wv_b, wo_b);

    k_qkv<<<768, 256, 0, stream>>>(query, key, value, wq_b, wk_b, wv_b,
                                   q_b, k_b, vT_b);

    float* attn_out = (float*)d_out + 4194304;
    attn_kernel<<<dim3(1024), 256, 0, stream>>>(q_b, k_b, vT_b, attn_out, ctx_b);

    k_out<<<dim3(512), 256, 0, stream>>>(ctx_b, wo_b, (float*)d_out);
}

// Round 13
// 195.826 us; speedup vs baseline: 2.2671x; 1.0716x over previous
//
#include <hip/hip_runtime.h>

// ---------------------------------------------------------------------------
// MHA forward. B=2 L=2048 D=1024 H=16 dk=dv=64.
// d_out = [out: 4194304 f32][attn: 134217728 f32]
// ws (40MB): wq|wk|wv|wo bf16 @0,2,4,6MB; q_b@8; k_b@16; vT@24; ctx@32
// Order: cvt_w -> fused QKV (Q prescaled by 0.125/ln2) -> attn (exp2) -> out
// attn: phase1 KVBLK=128 double-buffered (latency cover); phase2 = R10/R12
// counted-vmcnt NT-store pipeline. LDS unioned across phases (33.8KB, 4/CU).
// ---------------------------------------------------------------------------

typedef unsigned short u16;
typedef unsigned int   u32;
typedef __attribute__((ext_vector_type(4))) float f32x4;
typedef __attribute__((ext_vector_type(8))) u16   u16x8;
typedef __attribute__((ext_vector_type(4))) u16   u16x4;
typedef __attribute__((ext_vector_type(8))) __bf16 bf16x8;

#define MFMA16(a, b, c) __builtin_amdgcn_mfma_f32_16x16x32_bf16((a), (b), (c), 0, 0, 0)
#define VMCNT0 asm volatile("s_waitcnt vmcnt(0)" ::: "memory")
#define VMCNT4 asm volatile("s_waitcnt vmcnt(4)" ::: "memory")
#define LGKM0  asm volatile("s_waitcnt lgkmcnt(0)" ::: "memory")
#define SCHED0 __builtin_amdgcn_sched_barrier(0)
#define RAWBAR __builtin_amdgcn_s_barrier()

#if defined(__has_builtin)
#if __has_builtin(__builtin_amdgcn_global_load_lds)
#define HAS_GLL 1
#endif
#if __has_builtin(__builtin_amdgcn_exp2f)
#define EXP2(x) __builtin_amdgcn_exp2f(x)
#endif
#endif
#ifndef HAS_GLL
#define HAS_GLL 0
#endif
#ifndef EXP2
#define EXP2(x) __expf((x) * 0.69314718056f)
#endif

#define QSCALE 0.18033688011116f   // 0.125 / ln(2)

__device__ __forceinline__ u16 f2bf(float x) {
    u32 u = __builtin_bit_cast(u32, x);
    u += 0x7fffu + ((u >> 16) & 1u);   // RNE
    return (u16)(u >> 16);
}
__device__ __forceinline__ float bf2f(u16 x) {
    u32 u = ((u32)x) << 16;
    return __builtin_bit_cast(float, u);
}
__device__ __forceinline__ bf16x8 ld8(const u16* p) {
    return __builtin_bit_cast(bf16x8, *(const u16x8*)p);
}

// async global->LDS, 16B per lane; lds_base wave-uniform, HW adds lane*16.
__device__ __forceinline__ void stage16(const u16* g, u16* lds_base, int lane) {
#if HAS_GLL
    (void)lane;
    __builtin_amdgcn_global_load_lds(
        (const __attribute__((address_space(1))) u32*)g,
        (__attribute__((address_space(3))) u32*)lds_base, 16, 0, 0);
#else
    *(u16x8*)((char*)lds_base + lane * 16) = *(const u16x8*)g;
#endif
}

// ---------------- fp32 -> bf16 conversion (weights only) -------------------
__global__ __launch_bounds__(256) void cvt_w(
    const float* __restrict__ wq, const float* __restrict__ wk,
    const float* __restrict__ wv, const float* __restrict__ wo,
    u16* __restrict__ wqb, u16* __restrict__ wkb,
    u16* __restrict__ wvb, u16* __restrict__ wob) {
    int bid = blockIdx.x;
    const float* src; u16* dst; int base;
    if      (bid < 1024) { src = wq; dst = wqb; base = bid; }
    else if (bid < 2048) { src = wk; dst = wkb; base = bid - 1024; }
    else if (bid < 3072) { src = wv; dst = wvb; base = bid - 2048; }
    else                 { src = wo; dst = wob; base = bid - 3072; }
    int i = (base * 256 + threadIdx.x) * 4;
    float4 v = *(const float4*)(src + i);
    u16x4 h = { f2bf(v.x), f2bf(v.y), f2bf(v.z), f2bf(v.w) };
    *(u16x4*)(dst + i) = h;
}

// ---------------- fused QKV projection (R12 proven, XCD-pinned) ------------
__global__ __launch_bounds__(256)
void k_qkv(const float* __restrict__ qa, const float* __restrict__ ka,
           const float* __restrict__ va,
           const u16* __restrict__ wqp, const u16* __restrict__ wkp,
           const u16* __restrict__ wvp,
           u16* __restrict__ qo, u16* __restrict__ ko, u16* __restrict__ vTo) {
    constexpr int K = 1024;
    __shared__ u16 act_lds[2][128][32];
    __shared__ u16 w_lds[2][128][32];

    const int tid = threadIdx.x, lane = tid & 63, w = tid >> 6;
    const int wr = w >> 1, wc = w & 1, lr = lane & 15, g0 = lane >> 4;
    const int bid0 = blockIdx.x;
    const int kk = bid0 / 96, gg = bid0 % 96;      // XCD-pinned remap
    const int wgid = gg * 8 + kk;
    const int region = wgid >> 8, r = wgid & 255;
    const int act_r0 = (r >> 3) * 128, w_r0 = (r & 7) * 128;

    const float* actp = region == 0 ? qa : region == 1 ? ka : va;
    const u16*   wp   = region == 0 ? wqp : region == 1 ? wkp : wvp;

    const int srow = lane >> 2;
    const int scol = ((lane & 3) ^ ((lane >> 3) & 3)) * 8;
    const int arow = tid >> 1, ac0 = (tid & 1) * 16, lg0 = (tid & 1) * 2;
    const int apg0 = ((lg0)     ^ ((arow >> 1) & 3)) * 8;
    const int apg1 = ((lg0 + 1) ^ ((arow >> 1) & 3)) * 8;
    const int aph = (g0 ^ ((lr >> 1) & 3)) * 8;

    auto stage = [&](int kt, int buf) {
        #pragma unroll
        for (int c = 0; c < 2; ++c) {
            int rb = w * 16 + c * 64;
            stage16(wp + (size_t)(w_r0 + rb + srow) * K + kt * 32 + scol,
                    &w_lds[buf][rb][0], lane);
        }
        const float* as = actp + (size_t)(act_r0 + arow) * K + kt * 32 + ac0;
        f32x4 v0 = *(const f32x4*)as;
        f32x4 v1 = *(const f32x4*)(as + 4);
        f32x4 v2 = *(const f32x4*)(as + 8);
        f32x4 v3 = *(const f32x4*)(as + 12);
        u16x8 h0 = { f2bf(v0[0]), f2bf(v0[1]), f2bf(v0[2]), f2bf(v0[3]),
                     f2bf(v1[0]), f2bf(v1[1]), f2bf(v1[2]), f2bf(v1[3]) };
        u16x8 h1 = { f2bf(v2[0]), f2bf(v2[1]), f2bf(v2[2]), f2bf(v2[3]),
                     f2bf(v3[0]), f2bf(v3[1]), f2bf(v3[2]), f2bf(v3[3]) };
        *(u16x8*)&act_lds[buf][arow][apg0] = h0;
        *(u16x8*)&act_lds[buf][arow][apg1] = h1;
    };

    f32x4 acc[4][4] = {};
    stage(0, 0);
    VMCNT0;
    __syncthreads();

    for (int kt = 0; kt < 32; ++kt) {
        if (kt + 1 < 32) stage(kt + 1, (kt + 1) & 1);
        const int buf = kt & 1;
        const u16 (*ml)[32] = (region < 2) ? act_lds[buf] : w_lds[buf];
        const u16 (*nl)[32] = (region < 2) ? w_lds[buf]   : act_lds[buf];
        bf16x8 mf[4], nf[4];
        #pragma unroll
        for (int m = 0; m < 4; ++m) mf[m] = ld8(&ml[wr * 64 + m * 16 + lr][aph]);
        #pragma unroll
        for (int n = 0; n < 4; ++n) nf[n] = ld8(&nl[wc * 64 + n * 16 + lr][aph]);
        #pragma unroll
        for (int m = 0; m < 4; ++m)
            #pragma unroll
            for (int n = 0; n < 4; ++n)
                acc[m][n] = MFMA16(mf[m], nf[n], acc[m][n]);
        VMCNT0;
        __syncthreads();
    }

    const float sc = (region == 0) ? QSCALE : 1.0f;   // fold softmax scale into Q
    if (region < 2) {
        u16* dst = region == 0 ? qo : ko;
        #pragma unroll
        for (int m = 0; m < 4; ++m)
            #pragma unroll
            for (int n = 0; n < 4; ++n)
                #pragma unroll
                for (int rr = 0; rr < 4; ++rr) {
                    int grow = act_r0 + wr * 64 + m * 16 + g0 * 4 + rr;
                    int gcol = w_r0 + wc * 64 + n * 16 + lr;
                    size_t di = (size_t)((grow >> 11) * 16 + (gcol >> 6)) * 131072
                              + (size_t)(grow & 2047) * 64 + (gcol & 63);
                    dst[di] = f2bf(acc[m][n][rr] * sc);
                }
    } else {
        #pragma unroll
        for (int m = 0; m < 4; ++m)
            #pragma unroll
            for (int n = 0; n < 4; ++n)
                #pragma unroll
                for (int rr = 0; rr < 4; ++rr) {
                    int dvi = w_r0 + wr * 64 + m * 16 + g0 * 4 + rr;
                    int li  = act_r0 + wc * 64 + n * 16 + lr;
                    vTo[(size_t)dvi * 4096 + li] = f2bf(acc[m][n][rr]);
                }
    }
}

// ---------------- out projection (R12 proven, XCD-pinned 1D grid) ----------
__global__ __launch_bounds__(256)
void k_out(const u16* __restrict__ A, const u16* __restrict__ Bw,
           float* __restrict__ C) {
    constexpr int K = 1024;
    __shared__ u16 a_lds[2][128][32];
    __shared__ u16 b_lds[2][64][32];

    const int tid = threadIdx.x, lane = tid & 63, w = tid >> 6;
    const int wr = w >> 1, wc = w & 1, lr = lane & 15, g0 = lane >> 4;
    const int bid = blockIdx.x;
    const int m0 = (bid & 31) * 128, n0 = (bid >> 5) * 64;

    const int srow = lane >> 2;
    const int scol = ((lane & 3) ^ ((lane >> 3) & 3)) * 8;
    const int aph = (g0 ^ ((lr >> 1) & 3)) * 8;

    auto stage = [&](int kt, int buf) {
        #pragma unroll
        for (int c = 0; c < 2; ++c) {
            int rb = w * 16 + c * 64;
            stage16(A + (size_t)(m0 + rb + srow) * K + kt * 32 + scol,
                    &a_lds[buf][rb][0], lane);
        }
        int rb2 = w * 16;
        stage16(Bw + (size_t)(n0 + rb2 + srow) * K + kt * 32 + scol,
                &b_lds[buf][rb2][0], lane);
    };

    f32x4 acc[4][2] = {};
    stage(0, 0);
    VMCNT0;
    __syncthreads();

    for (int kt = 0; kt < 32; ++kt) {
        if (kt + 1 < 32) stage(kt + 1, (kt + 1) & 1);
        const int buf = kt & 1;
        bf16x8 mf[4], nf[2];
        #pragma unroll
        for (int m = 0; m < 4; ++m) mf[m] = ld8(&a_lds[buf][wr * 64 + m * 16 + lr][aph]);
        #pragma unroll
        for (int n = 0; n < 2; ++n) nf[n] = ld8(&b_lds[buf][wc * 32 + n * 16 + lr][aph]);
        #pragma unroll
        for (int m = 0; m < 4; ++m)
            #pragma unroll
            for (int n = 0; n < 2; ++n)
                acc[m][n] = MFMA16(mf[m], nf[n], acc[m][n]);
        VMCNT0;
        __syncthreads();
    }

    #pragma unroll
    for (int m = 0; m < 4; ++m)
        #pragma unroll
        for (int n = 0; n < 2; ++n)
            #pragma unroll
            for (int rr = 0; rr < 4; ++rr) {
                int grow = m0 + wr * 64 + m * 16 + g0 * 4 + rr;
                int gcol = n0 + wc * 32 + n * 16 + lr;
                C[(size_t)grow * 1024 + gcol] = acc[m][n][rr];
            }
}

// ---------------- fused attention -----------------------------------------
// 1024 blocks XCD-pinned, 4 waves x 16 q-rows, 4 blocks/CU (33.8 KB LDS).
// Phase 1: KVBLK=128 double-buffered denominator pass (prefetch covered by
// 16 MFMA + 32 exp per iter). Phase 2: R10/R12 KVBLK=64 counted-vmcnt
// NT-store pipeline. LDS unioned across phases (sequential use).
__global__ __launch_bounds__(256, 4)
void attn_kernel(const u16* __restrict__ qw, const u16* __restrict__ kw,
                 const u16* __restrict__ vT, float* __restrict__ attn_o,
                 u16* __restrict__ ctx_o) {
    constexpr int L = 2048;
    // union: phase1 k1[2][128][64] (32768B) | phase2 k2(16384)+vt(8192)+p(9216)
    __shared__ __attribute__((aligned(16))) char smem[33792];
    typedef u16 K1Row[64];
    K1Row* k1b0 = (K1Row*)smem;                       // k1[0][128][64]
    K1Row* k1b1 = (K1Row*)(smem + 16384);             // k1[1][128][64]
    K1Row* k2b0 = (K1Row*)smem;                       // k2[0][64][64]
    K1Row* k2b1 = (K1Row*)(smem + 8192);              // k2[1][64][64]
    K1Row* vt   = (K1Row*)(smem + 16384);             // vt[64][64]
    typedef u16 PRow[72];
    PRow* pl = (PRow*)(smem + 24576);                 // p[4*16][72]

    const int tid = threadIdx.x, w = tid >> 6, lane = tid & 63;
    const int bid = blockIdx.x;
    const int bh = (bid & 7) + 8 * (bid >> 8);     // XCD-pinned
    const int qb = (bid >> 3) & 31;
    const int b = bh >> 4, h = bh & 15;
    const int qr0 = qb * 64 + w * 16;
    const int lr = lane & 15, g0 = lane >> 4;

    const u16* kbh = kw + (size_t)bh * L * 64;
    const u16* vbh = vT + (size_t)(h * 64) * 4096 + b * 2048;

    const int srow8 = lane >> 3;                   // 0..7
    const int scol8 = ((lane & 7) ^ srow8) * 8;    // pre-swizzled src granule
    const int kph0 = (g0 ^ (lr & 7)) * 8;
    const int kph1 = ((g0 + 4) ^ (lr & 7)) * 8;

    size_t qbase = ((size_t)bh * L + qr0 + lr) * 64 + g0 * 8;
    bf16x8 aq0 = ld8(qw + qbase);
    bf16x8 aq1 = ld8(qw + qbase + 32);

    PRow* plw = pl + w * 16;

    // ---------------- phase 1: softmax denominator, KVBLK=128 --------------
    auto stageK1 = [&](int kv, K1Row* dst) {
        #pragma unroll
        for (int c = 0; c < 4; ++c) {
            int rb = c * 32 + w * 8;
            stage16(kbh + (size_t)(kv + rb + srow8) * 64 + scol8, &dst[rb][0], lane);
        }
    };
    float ssum = 0.f;
    stageK1(0, k1b0);
    VMCNT0;
    __syncthreads();
    for (int t = 0; t < 16; ++t) {
        if (t + 1 < 16) stageK1((t + 1) * 128, (t & 1) ? k1b0 : k1b1);
        K1Row* kb = (t & 1) ? k1b1 : k1b0;
        f32x4 sacc[8] = {};
        #pragma unroll
        for (int n = 0; n < 8; ++n) {
            const u16* krow = &kb[n * 16 + lr][0];
            sacc[n] = MFMA16(ld8(krow + kph0), aq0, sacc[n]);   // swapped: S^T
            sacc[n] = MFMA16(ld8(krow + kph1), aq1, sacc[n]);
        }
        #pragma unroll
        for (int n = 0; n < 8; ++n)
            #pragma unroll
            for (int rr = 0; rr < 4; ++rr)
                ssum += EXP2(sacc[n][rr]);
        VMCNT0;            // prefetch had 16 MFMA + 32 exp of cover
        __syncthreads();
    }
    ssum += __shfl_xor(ssum, 16);
    ssum += __shfl_xor(ssum, 32);
    const float rinv = 1.f / ssum;

    // ---------------- phase 2: attn write + PV (R10/R12 structure) ---------
    auto stageK = [&](int kv, K1Row* dst) {
        #pragma unroll
        for (int c = 0; c < 2; ++c) {
            int rb = c * 32 + w * 8;
            stage16(kbh + (size_t)(kv + rb + srow8) * 64 + scol8, &dst[rb][0], lane);
        }
    };
    auto stageV = [&](int kv) {
        #pragma unroll
        for (int c = 0; c < 2; ++c) {
            int rb = w * 16 + c * 8;
            stage16(vbh + (size_t)(rb + srow8) * 4096 + kv + scol8, &vt[rb][0], lane);
        }
    };

    f32x4 cacc[4] = {};
    float* attn_b = attn_o + (size_t)bh * L * L;
    stageK(0, k2b0);
    VMCNT0;
    __syncthreads();

    for (int t = 0; t < 32; ++t) {
        const int kv = t * 64;
        K1Row* kb = (t & 1) ? k2b1 : k2b0;
        // loads FIRST (oldest in vm queue -> drained by vmcnt(4))
        stageV(kv);
        if (t + 1 < 32) stageK(kv + 64, (t & 1) ? k2b0 : k2b1);
        SCHED0;                        // keep stores below the gll issues
        // deferred NT writeout of tile t-1 (stores stay in flight past barrier)
        if (t > 0) {
            const int kvp = kv - 64;
            #pragma unroll
            for (int rep = 0; rep < 4; ++rep) {
                int row = rep * 4 + g0;
                u16x4 pv4 = *(const u16x4*)&plw[row][lr * 4];
                f32x4 f0 = { bf2f(pv4[0]), bf2f(pv4[1]), bf2f(pv4[2]), bf2f(pv4[3]) };
                __builtin_nontemporal_store(
                    f0, (f32x4*)(attn_b + (size_t)(qr0 + row) * L + kvp + lr * 4));
            }
        }
        // QK^T on current tile
        f32x4 sacc[4] = {};
        #pragma unroll
        for (int n = 0; n < 4; ++n) {
            const u16* krow = &kb[n * 16 + lr][0];
            sacc[n] = MFMA16(ld8(krow + kph0), aq0, sacc[n]);
            sacc[n] = MFMA16(ld8(krow + kph1), aq1, sacc[n]);
        }
        // drain the 4 gll loads; allow the 4 stores to stay in flight
        if (t == 0) { VMCNT0; } else { VMCNT4; }
        SCHED0; RAWBAR; SCHED0;        // mid barrier (no full vm drain)

        // normalized P (bf16) -> p_lds[q=lr][kv]
        #pragma unroll
        for (int n = 0; n < 4; ++n) {
            float p0 = EXP2(sacc[n][0]) * rinv;
            float p1 = EXP2(sacc[n][1]) * rinv;
            float p2 = EXP2(sacc[n][2]) * rinv;
            float p3 = EXP2(sacc[n][3]) * rinv;
            u16x4 pk = { f2bf(p0), f2bf(p1), f2bf(p2), f2bf(p3) };
            *(u16x4*)&plw[lr][n * 16 + g0 * 4] = pk;
        }
        // PV: ctx[q][dv] += P[q][kv] * V^T[dv][kv]
        #pragma unroll
        for (int kk = 0; kk < 2; ++kk) {
            bf16x8 ap = ld8(&plw[lr][kk * 32 + g0 * 8]);
            const int vph = ((kk * 4 + g0) ^ (lr & 7)) * 8;
            #pragma unroll
            for (int n2 = 0; n2 < 4; ++n2) {
                bf16x8 bv = ld8(&vt[n2 * 16 + lr][vph]);
                cacc[n2] = MFMA16(ap, bv, cacc[n2]);
            }
        }
        LGKM0;                          // DS retired -> vt/k2 safe to restage
        SCHED0; RAWBAR; SCHED0;         // end barrier (stores still in flight)
    }
    // final NT writeout (tile 31)
    #pragma unroll
    for (int rep = 0; rep < 4; ++rep) {
        int row = rep * 4 + g0;
        u16x4 pv4 = *(const u16x4*)&plw[row][lr * 4];
        f32x4 f0 = { bf2f(pv4[0]), bf2f(pv4[1]), bf2f(pv4[2]), bf2f(pv4[3]) };
        __builtin_nontemporal_store(
            f0, (f32x4*)(attn_b + (size_t)(qr0 + row) * L + (L - 64) + lr * 4));
    }

    // ctx -> ws in [b][l][h*64+dv] layout (normal stores; consumed by k_out)
    #pragma unroll
    for (int n2 = 0; n2 < 4; ++n2)
        #pragma unroll
        for (int rr = 0; rr < 4; ++rr)
            ctx_o[((size_t)b * L + qr0 + g0 * 4 + rr) * 1024 + h * 64 + n2 * 16 + lr]
                = f2bf(cacc[n2][rr]);
}

// ---------------------------------------------------------------------------
extern "C" void kernel_launch(void* const* d_in, const int* in_sizes, int n_in,
                              void* d_out, int out_size, void* d_ws, size_t ws_size,
                              hipStream_t stream) {
    const float* key   = (const float*)d_in[0];
    const float* value = (const float*)d_in[1];
    const float* query = (const float*)d_in[2];
    const float* wq    = (const float*)d_in[3];
    const float* wk    = (const float*)d_in[4];
    const float* wv    = (const float*)d_in[5];
    const float* wo    = (const float*)d_in[6];

    char* ws = (char*)d_ws;
    const size_t MB = 1024 * 1024;
    u16* wq_b = (u16*)(ws + 0 * MB);
    u16* wk_b = (u16*)(ws + 2 * MB);
    u16* wv_b = (u16*)(ws + 4 * MB);
    u16* wo_b = (u16*)(ws + 6 * MB);
    u16* q_b  = (u16*)(ws + 8 * MB);
    u16* k_b  = (u16*)(ws + 16 * MB);
    u16* vT_b = (u16*)(ws + 24 * MB);
    u16* ctx_b= (u16*)(ws + 32 * MB);

    cvt_w<<<4096, 256, 0, stream>>>(wq, wk, wv, wo, wq_b, wk_b, wv_b, wo_b);

    k_qkv<<<768, 256, 0, stream>>>(query, key, value, wq_b, wk_b, wv_b,
                                   q_b, k_b, vT_b);

    float* attn_out = (float*)d_out + 4194304;
    attn_kernel<<<dim3(1024), 256, 0, stream>>>(q_b, k_b, vT_b, attn_out, ctx_b);

    k_out<<<dim3(512), 256, 0, stream>>>(ctx_b, wo_b, (float*)d_out);
}

// Round 15
// 195.148 us; speedup vs baseline: 2.2749x; 1.0035x over previous
//
#include <hip/hip_runtime.h>

// ---------------------------------------------------------------------------
// MHA forward. B=2 L=2048 D=1024 H=16 dk=dv=64.
// d_out = [out: 4194304 f32][attn: 134217728 f32]
// ws (40MB): wq|wk|wv|wo bf16 @0,2,4,6MB; q_b@8; k_b@16; vT@24; ctx@32
// Order: cvt_w -> fused QKV (Q prescaled by 0.125/ln2) -> attn (exp2) -> out
// attn: phase1 KVBLK=128 dbuf (R13); phase2 single-barrier loop with BOTH
// K and V double-buffered (41.9KB LDS, 3/CU), counted-vmcnt NT-store pipe.
// NOTE: no arrays-of-LDS-pointers (gfx950 static-initializer limitation) --
// scalar pointers + ternary select instead.
// ---------------------------------------------------------------------------

typedef unsigned short u16;
typedef unsigned int   u32;
typedef __attribute__((ext_vector_type(4))) float f32x4;
typedef __attribute__((ext_vector_type(8))) u16   u16x8;
typedef __attribute__((ext_vector_type(4))) u16   u16x4;
typedef __attribute__((ext_vector_type(8))) __bf16 bf16x8;

#define MFMA16(a, b, c) __builtin_amdgcn_mfma_f32_16x16x32_bf16((a), (b), (c), 0, 0, 0)
#define VMCNT0 asm volatile("s_waitcnt vmcnt(0)" ::: "memory")
#define VMCNT4 asm volatile("s_waitcnt vmcnt(4)" ::: "memory")
#define SCHED0 __builtin_amdgcn_sched_barrier(0)
#define RAWBAR __builtin_amdgcn_s_barrier()

#if defined(__has_builtin)
#if __has_builtin(__builtin_amdgcn_global_load_lds)
#define HAS_GLL 1
#endif
#if __has_builtin(__builtin_amdgcn_exp2f)
#define EXP2(x) __builtin_amdgcn_exp2f(x)
#endif
#endif
#ifndef HAS_GLL
#define HAS_GLL 0
#endif
#ifndef EXP2
#define EXP2(x) __expf((x) * 0.69314718056f)
#endif

#define QSCALE 0.18033688011116f   // 0.125 / ln(2)

__device__ __forceinline__ u16 f2bf(float x) {
    u32 u = __builtin_bit_cast(u32, x);
    u += 0x7fffu + ((u >> 16) & 1u);   // RNE
    return (u16)(u >> 16);
}
__device__ __forceinline__ float bf2f(u16 x) {
    u32 u = ((u32)x) << 16;
    return __builtin_bit_cast(float, u);
}
__device__ __forceinline__ bf16x8 ld8(const u16* p) {
    return __builtin_bit_cast(bf16x8, *(const u16x8*)p);
}

// async global->LDS, 16B per lane; lds_base wave-uniform, HW adds lane*16.
__device__ __forceinline__ void stage16(const u16* g, u16* lds_base, int lane) {
#if HAS_GLL
    (void)lane;
    __builtin_amdgcn_global_load_lds(
        (const __attribute__((address_space(1))) u32*)g,
        (__attribute__((address_space(3))) u32*)lds_base, 16, 0, 0);
#else
    *(u16x8*)((char*)lds_base + lane * 16) = *(const u16x8*)g;
#endif
}

// ---------------- fp32 -> bf16 conversion (weights only) -------------------
__global__ __launch_bounds__(256) void cvt_w(
    const float* __restrict__ wq, const float* __restrict__ wk,
    const float* __restrict__ wv, const float* __restrict__ wo,
    u16* __restrict__ wqb, u16* __restrict__ wkb,
    u16* __restrict__ wvb, u16* __restrict__ wob) {
    int bid = blockIdx.x;
    const float* src; u16* dst; int base;
    if      (bid < 1024) { src = wq; dst = wqb; base = bid; }
    else if (bid < 2048) { src = wk; dst = wkb; base = bid - 1024; }
    else if (bid < 3072) { src = wv; dst = wvb; base = bid - 2048; }
    else                 { src = wo; dst = wob; base = bid - 3072; }
    int i = (base * 256 + threadIdx.x) * 4;
    float4 v = *(const float4*)(src + i);
    u16x4 h = { f2bf(v.x), f2bf(v.y), f2bf(v.z), f2bf(v.w) };
    *(u16x4*)(dst + i) = h;
}

// ---------------- fused QKV projection (R12/R13 proven, XCD-pinned) --------
__global__ __launch_bounds__(256)
void k_qkv(const float* __restrict__ qa, const float* __restrict__ ka,
           const float* __restrict__ va,
           const u16* __restrict__ wqp, const u16* __restrict__ wkp,
           const u16* __restrict__ wvp,
           u16* __restrict__ qo, u16* __restrict__ ko, u16* __restrict__ vTo) {
    constexpr int K = 1024;
    __shared__ u16 act_lds[2][128][32];
    __shared__ u16 w_lds[2][128][32];

    const int tid = threadIdx.x, lane = tid & 63, w = tid >> 6;
    const int wr = w >> 1, wc = w & 1, lr = lane & 15, g0 = lane >> 4;
    const int bid0 = blockIdx.x;
    const int kk = bid0 / 96, gg = bid0 % 96;      // XCD-pinned remap
    const int wgid = gg * 8 + kk;
    const int region = wgid >> 8, r = wgid & 255;
    const int act_r0 = (r >> 3) * 128, w_r0 = (r & 7) * 128;

    const float* actp = region == 0 ? qa : region == 1 ? ka : va;
    const u16*   wp   = region == 0 ? wqp : region == 1 ? wkp : wvp;

    const int srow = lane >> 2;
    const int scol = ((lane & 3) ^ ((lane >> 3) & 3)) * 8;
    const int arow = tid >> 1, ac0 = (tid & 1) * 16, lg0 = (tid & 1) * 2;
    const int apg0 = ((lg0)     ^ ((arow >> 1) & 3)) * 8;
    const int apg1 = ((lg0 + 1) ^ ((arow >> 1) & 3)) * 8;
    const int aph = (g0 ^ ((lr >> 1) & 3)) * 8;

    auto stage = [&](int kt, int buf) {
        #pragma unroll
        for (int c = 0; c < 2; ++c) {
            int rb = w * 16 + c * 64;
            stage16(wp + (size_t)(w_r0 + rb + srow) * K + kt * 32 + scol,
                    &w_lds[buf][rb][0], lane);
        }
        const float* as = actp + (size_t)(act_r0 + arow) * K + kt * 32 + ac0;
        f32x4 v0 = *(const f32x4*)as;
        f32x4 v1 = *(const f32x4*)(as + 4);
        f32x4 v2 = *(const f32x4*)(as + 8);
        f32x4 v3 = *(const f32x4*)(as + 12);
        u16x8 h0 = { f2bf(v0[0]), f2bf(v0[1]), f2bf(v0[2]), f2bf(v0[3]),
                     f2bf(v1[0]), f2bf(v1[1]), f2bf(v1[2]), f2bf(v1[3]) };
        u16x8 h1 = { f2bf(v2[0]), f2bf(v2[1]), f2bf(v2[2]), f2bf(v2[3]),
                     f2bf(v3[0]), f2bf(v3[1]), f2bf(v3[2]), f2bf(v3[3]) };
        *(u16x8*)&act_lds[buf][arow][apg0] = h0;
        *(u16x8*)&act_lds[buf][arow][apg1] = h1;
    };

    f32x4 acc[4][4] = {};
    stage(0, 0);
    VMCNT0;
    __syncthreads();

    for (int kt = 0; kt < 32; ++kt) {
        if (kt + 1 < 32) stage(kt + 1, (kt + 1) & 1);
        const int buf = kt & 1;
        const u16 (*ml)[32] = (region < 2) ? act_lds[buf] : w_lds[buf];
        const u16 (*nl)[32] = (region < 2) ? w_lds[buf]   : act_lds[buf];
        bf16x8 mf[4], nf[4];
        #pragma unroll
        for (int m = 0; m < 4; ++m) mf[m] = ld8(&ml[wr * 64 + m * 16 + lr][aph]);
        #pragma unroll
        for (int n = 0; n < 4; ++n) nf[n] = ld8(&nl[wc * 64 + n * 16 + lr][aph]);
        #pragma unroll
        for (int m = 0; m < 4; ++m)
            #pragma unroll
            for (int n = 0; n < 4; ++n)
                acc[m][n] = MFMA16(mf[m], nf[n], acc[m][n]);
        VMCNT0;
        __syncthreads();
    }

    const float sc = (region == 0) ? QSCALE : 1.0f;   // fold softmax scale into Q
    if (region < 2) {
        u16* dst = region == 0 ? qo : ko;
        #pragma unroll
        for (int m = 0; m < 4; ++m)
            #pragma unroll
            for (int n = 0; n < 4; ++n)
                #pragma unroll
                for (int rr = 0; rr < 4; ++rr) {
                    int grow = act_r0 + wr * 64 + m * 16 + g0 * 4 + rr;
                    int gcol = w_r0 + wc * 64 + n * 16 + lr;
                    size_t di = (size_t)((grow >> 11) * 16 + (gcol >> 6)) * 131072
                              + (size_t)(grow & 2047) * 64 + (gcol & 63);
                    dst[di] = f2bf(acc[m][n][rr] * sc);
                }
    } else {
        #pragma unroll
        for (int m = 0; m < 4; ++m)
            #pragma unroll
            for (int n = 0; n < 4; ++n)
                #pragma unroll
                for (int rr = 0; rr < 4; ++rr) {
                    int dvi = w_r0 + wr * 64 + m * 16 + g0 * 4 + rr;
                    int li  = act_r0 + wc * 64 + n * 16 + lr;
                    vTo[(size_t)dvi * 4096 + li] = f2bf(acc[m][n][rr]);
                }
    }
}

// ---------------- out projection (R12/R13 proven, XCD-pinned 1D grid) ------
__global__ __launch_bounds__(256)
void k_out(const u16* __restrict__ A, const u16* __restrict__ Bw,
           float* __restrict__ C) {
    constexpr int K = 1024;
    __shared__ u16 a_lds[2][128][32];
    __shared__ u16 b_lds[2][64][32];

    const int tid = threadIdx.x, lane = tid & 63, w = tid >> 6;
    const int wr = w >> 1, wc = w & 1, lr = lane & 15, g0 = lane >> 4;
    const int bid = blockIdx.x;
    const int m0 = (bid & 31) * 128, n0 = (bid >> 5) * 64;

    const int srow = lane >> 2;
    const int scol = ((lane & 3) ^ ((lane >> 3) & 3)) * 8;
    const int aph = (g0 ^ ((lr >> 1) & 3)) * 8;

    auto stage = [&](int kt, int buf) {
        #pragma unroll
        for (int c = 0; c < 2; ++c) {
            int rb = w * 16 + c * 64;
            stage16(A + (size_t)(m0 + rb + srow) * K + kt * 32 + scol,
                    &a_lds[buf][rb][0], lane);
        }
        int rb2 = w * 16;
        stage16(Bw + (size_t)(n0 + rb2 + srow) * K + kt * 32 + scol,
                &b_lds[buf][rb2][0], lane);
    };

    f32x4 acc[4][2] = {};
    stage(0, 0);
    VMCNT0;
    __syncthreads();

    for (int kt = 0; kt < 32; ++kt) {
        if (kt + 1 < 32) stage(kt + 1, (kt + 1) & 1);
        const int buf = kt & 1;
        bf16x8 mf[4], nf[2];
        #pragma unroll
        for (int m = 0; m < 4; ++m) mf[m] = ld8(&a_lds[buf][wr * 64 + m * 16 + lr][aph]);
        #pragma unroll
        for (int n = 0; n < 2; ++n) nf[n] = ld8(&b_lds[buf][wc * 32 + n * 16 + lr][aph]);
        #pragma unroll
        for (int m = 0; m < 4; ++m)
            #pragma unroll
            for (int n = 0; n < 2; ++n)
                acc[m][n] = MFMA16(mf[m], nf[n], acc[m][n]);
        VMCNT0;
        __syncthreads();
    }

    #pragma unroll
    for (int m = 0; m < 4; ++m)
        #pragma unroll
        for (int n = 0; n < 2; ++n)
            #pragma unroll
            for (int rr = 0; rr < 4; ++rr) {
                int grow = m0 + wr * 64 + m * 16 + g0 * 4 + rr;
                int gcol = n0 + wc * 32 + n * 16 + lr;
                C[(size_t)grow * 1024 + gcol] = acc[m][n][rr];
            }
}

// ---------------- fused attention -----------------------------------------
// 1024 blocks XCD-pinned, 4 waves x 16 q-rows, 3 blocks/CU (41.9 KB LDS).
// Phase 1: KVBLK=128 dbuf denominator pass (R13). Phase 2: SINGLE barrier
// per tile; K and V both double-buffered; NT stores(t-1) ride past the
// barrier via vmcnt(4) (loads issued first = oldest = drained).
__global__ __launch_bounds__(256, 3)
void attn_kernel(const u16* __restrict__ qw, const u16* __restrict__ kw,
                 const u16* __restrict__ vT, float* __restrict__ attn_o,
                 u16* __restrict__ ctx_o) {
    constexpr int L = 2048;
    // union: phase1 k1[2][128][64] (32768B) | phase2 k2 x2 (16K) + vt x2 (16K);
    // p @32768 (9216B). Scalar LDS pointers only (no pointer arrays).
    __shared__ __attribute__((aligned(16))) char smem[41984];
    typedef u16 KRow[64];
    KRow* k1b0 = (KRow*)smem;                         // phase1 buf0 [128][64]
    KRow* k1b1 = (KRow*)(smem + 16384);               // phase1 buf1 [128][64]
    KRow* k2b0 = (KRow*)smem;                         // phase2 K buf0 [64][64]
    KRow* k2b1 = (KRow*)(smem + 8192);                // phase2 K buf1 [64][64]
    KRow* vtb0 = (KRow*)(smem + 16384);               // phase2 V buf0 [64][64]
    KRow* vtb1 = (KRow*)(smem + 24576);               // phase2 V buf1 [64][64]
    typedef u16 PRow[72];
    PRow* pl = (PRow*)(smem + 32768);                 // p[4*16][72]

    const int tid = threadIdx.x, w = tid >> 6, lane = tid & 63;
    const int bid = blockIdx.x;
    const int bh = (bid & 7) + 8 * (bid >> 8);     // XCD-pinned
    const int qb = (bid >> 3) & 31;
    const int b = bh >> 4, h = bh & 15;
    const int qr0 = qb * 64 + w * 16;
    const int lr = lane & 15, g0 = lane >> 4;

    const u16* kbh = kw + (size_t)bh * L * 64;
    const u16* vbh = vT + (size_t)(h * 64) * 4096 + b * 2048;

    const int srow8 = lane >> 3;                   // 0..7
    const int scol8 = ((lane & 7) ^ srow8) * 8;    // pre-swizzled src granule
    const int kph0 = (g0 ^ (lr & 7)) * 8;
    const int kph1 = ((g0 + 4) ^ (lr & 7)) * 8;

    size_t qbase = ((size_t)bh * L + qr0 + lr) * 64 + g0 * 8;
    bf16x8 aq0 = ld8(qw + qbase);
    bf16x8 aq1 = ld8(qw + qbase + 32);

    PRow* plw = pl + w * 16;

    // ---------------- phase 1: softmax denominator, KVBLK=128 --------------
    auto stageK1 = [&](int kv, KRow* dst) {
        #pragma unroll
        for (int c = 0; c < 4; ++c) {
            int rb = c * 32 + w * 8;
            stage16(kbh + (size_t)(kv + rb + srow8) * 64 + scol8, &dst[rb][0], lane);
        }
    };
    float ssum = 0.f;
    stageK1(0, k1b0);
    VMCNT0;
    __syncthreads();
    for (int t = 0; t < 16; ++t) {
        if (t + 1 < 16) stageK1((t + 1) * 128, (t & 1) ? k1b0 : k1b1);
        KRow* kb = (t & 1) ? k1b1 : k1b0;
        f32x4 sacc[8] = {};
        #pragma unroll
        for (int n = 0; n < 8; ++n) {
            const u16* krow = &kb[n * 16 + lr][0];
            sacc[n] = MFMA16(ld8(krow + kph0), aq0, sacc[n]);   // swapped: S^T
            sacc[n] = MFMA16(ld8(krow + kph1), aq1, sacc[n]);
        }
        #pragma unroll
        for (int n = 0; n < 8; ++n)
            #pragma unroll
            for (int rr = 0; rr < 4; ++rr)
                ssum += EXP2(sacc[n][rr]);
        VMCNT0;            // prefetch had 16 MFMA + 32 exp of cover
        __syncthreads();
    }
    ssum += __shfl_xor(ssum, 16);
    ssum += __shfl_xor(ssum, 32);
    const float rinv = 1.f / ssum;

    // ---------------- phase 2: single-barrier dbuf loop ---------------------
    auto stageK = [&](int kv, KRow* dst) {
        #pragma unroll
        for (int c = 0; c < 2; ++c) {
            int rb = c * 32 + w * 8;
            stage16(kbh + (size_t)(kv + rb + srow8) * 64 + scol8, &dst[rb][0], lane);
        }
    };
    auto stageV = [&](int kv, KRow* dst) {
        #pragma unroll
        for (int c = 0; c < 2; ++c) {
            int rb = w * 16 + c * 8;
            stage16(vbh + (size_t)(rb + srow8) * 4096 + kv + scol8, &dst[rb][0], lane);
        }
    };

    f32x4 cacc[4] = {};
    float* attn_b = attn_o + (size_t)bh * L * L;
    stageK(0, k2b0);
    stageV(0, vtb0);
    VMCNT0;
    __syncthreads();

    for (int t = 0; t < 32; ++t) {
        const int kv = t * 64, buf = t & 1;
        KRow* kcur = buf ? k2b1 : k2b0;
        KRow* vcur = buf ? vtb1 : vtb0;
        // loads for t+1 FIRST (oldest in vm queue -> drained by vmcnt(4))
        if (t + 1 < 32) {
            stageV(kv + 64, buf ? vtb0 : vtb1);
            stageK(kv + 64, buf ? k2b0 : k2b1);
        }
        SCHED0;                        // keep stores below the gll issues
        // deferred NT writeout of tile t-1 (stores ride past the barrier)
        if (t > 0) {
            const int kvp = kv - 64;
            #pragma unroll
            for (int rep = 0; rep < 4; ++rep) {
                int row = rep * 4 + g0;
                u16x4 pv4 = *(const u16x4*)&plw[row][lr * 4];
                f32x4 f0 = { bf2f(pv4[0]), bf2f(pv4[1]), bf2f(pv4[2]), bf2f(pv4[3]) };
                __builtin_nontemporal_store(
                    f0, (f32x4*)(attn_b + (size_t)(qr0 + row) * L + kvp + lr * 4));
            }
        }
        // QK^T on current tile (kcur guaranteed by previous barrier)
        f32x4 sacc[4] = {};
        #pragma unroll
        for (int n = 0; n < 4; ++n) {
            const u16* krow = &kcur[n * 16 + lr][0];
            sacc[n] = MFMA16(ld8(krow + kph0), aq0, sacc[n]);
            sacc[n] = MFMA16(ld8(krow + kph1), aq1, sacc[n]);
        }
        // normalized P (bf16) -> p_lds[q=lr][kv] (per-wave region)
        #pragma unroll
        for (int n = 0; n < 4; ++n) {
            float p0 = EXP2(sacc[n][0]) * rinv;
            float p1 = EXP2(sacc[n][1]) * rinv;
            float p2 = EXP2(sacc[n][2]) * rinv;
            float p3 = EXP2(sacc[n][3]) * rinv;
            u16x4 pk = { f2bf(p0), f2bf(p1), f2bf(p2), f2bf(p3) };
            *(u16x4*)&plw[lr][n * 16 + g0 * 4] = pk;
        }
        // PV: ctx[q][dv] += P[q][kv] * V^T[dv][kv]  (vcur from prev barrier)
        #pragma unroll
        for (int kk = 0; kk < 2; ++kk) {
            bf16x8 ap = ld8(&plw[lr][kk * 32 + g0 * 8]);
            const int vph = ((kk * 4 + g0) ^ (lr & 7)) * 8;
            #pragma unroll
            for (int n2 = 0; n2 < 4; ++n2) {
                bf16x8 bv = ld8(&vcur[n2 * 16 + lr][vph]);
                cacc[n2] = MFMA16(ap, bv, cacc[n2]);
            }
        }
        // drain this iteration's 4 gll loads; stores(t-1) stay in flight
        if (t == 0) { VMCNT0; } else { VMCNT4; }
        SCHED0; RAWBAR; SCHED0;        // the ONE barrier per tile
    }
    // final NT writeout (tile 31)
    #pragma unroll
    for (int rep = 0; rep < 4; ++rep) {
        int row = rep * 4 + g0;
        u16x4 pv4 = *(const u16x4*)&plw[row][lr * 4];
        f32x4 f0 = { bf2f(pv4[0]), bf2f(pv4[1]), bf2f(pv4[2]), bf2f(pv4[3]) };
        __builtin_nontemporal_store(
            f0, (f32x4*)(attn_b + (size_t)(qr0 + row) * L + (L - 64) + lr * 4));
    }

    // ctx -> ws in [b][l][h*64+dv] layout (normal stores; consumed by k_out)
    #pragma unroll
    for (int n2 = 0; n2 < 4; ++n2)
        #pragma unroll
        for (int rr = 0; rr < 4; ++rr)
            ctx_o[((size_t)b * L + qr0 + g0 * 4 + rr) * 1024 + h * 64 + n2 * 16 + lr]
                = f2bf(cacc[n2][rr]);
}

// ---------------------------------------------------------------------------
extern "C" void kernel_launch(void* const* d_in, const int* in_sizes, int n_in,
                              void* d_out, int out_size, void* d_ws, size_t ws_size,
                              hipStream_t stream) {
    const float* key   = (const float*)d_in[0];
    const float* value = (const float*)d_in[1];
    const float* query = (const float*)d_in[2];
    const float* wq    = (const float*)d_in[3];
    const float* wk    = (const float*)d_in[4];
    const float* wv    = (const float*)d_in[5];
    const float* wo    = (const float*)d_in[6];

    char* ws = (char*)d_ws;
    const size_t MB = 1024 * 1024;
    u16* wq_b = (u16*)(ws + 0 * MB);
    u16* wk_b = (u16*)(ws + 2 * MB);
    u16* wv_b = (u16*)(ws + 4 * MB);
    u16* wo_b = (u16*)(ws + 6 * MB);
    u16* q_b  = (u16*)(ws + 8 * MB);
    u16* k_b  = (u16*)(ws + 16 * MB);
    u16* vT_b = (u16*)(ws + 24 * MB);
    u16* ctx_b= (u16*)(ws + 32 * MB);

    cvt_w<<<4096, 256, 0, stream>>>(wq, wk, wv, wo, wq_b, wk_b, wv_b, wo_b);

    k_qkv<<<768, 256, 0, stream>>>(query, key, value, wq_b, wk_b, wv_b,
                                   q_b, k_b, vT_b);

    float* attn_out = (float*)d_out + 4194304;
    attn_kernel<<<dim3(1024), 256, 0, stream>>>(q_b, k_b, vT_b, attn_out, ctx_b);

    k_out<<<dim3(512), 256, 0, stream>>>(ctx_b, wo_b, (float*)d_out);
}